// Round 1
// baseline (45.525 us; speedup 1.0000x reference)
//
#include <hip/hip_runtime.h>

// FixedSizeAggregation: reference does
//   order = argsort(batch, stable)  -- batch = repeat(arange(B), N_PER), already
//                                      sorted -> order == identity
//   out = x[order].reshape(B, N_PER*D)  -- flat memory identical to x
// => the op is an exact flat copy of x (float32, B*N_PER*D elements) to d_out.
// Memory-bound: 128 MiB read + 128 MiB write. float4 grid-stride copy.

__global__ void fixed_size_agg_copy_kernel(const float4* __restrict__ src,
                                           float4* __restrict__ dst,
                                           long long n_vec) {
    long long i = (long long)blockIdx.x * blockDim.x + threadIdx.x;
    long long stride = (long long)gridDim.x * blockDim.x;
    for (; i < n_vec; i += stride) {
        dst[i] = src[i];
    }
}

__global__ void fixed_size_agg_tail_kernel(const float* __restrict__ src,
                                           float* __restrict__ dst,
                                           long long start, long long n) {
    long long i = start + (long long)blockIdx.x * blockDim.x + threadIdx.x;
    if (i < n) dst[i] = src[i];
}

extern "C" void kernel_launch(void* const* d_in, const int* in_sizes, int n_in,
                              void* d_out, int out_size, void* d_ws, size_t ws_size,
                              hipStream_t stream) {
    const float* x = (const float*)d_in[0];
    float* out = (float*)d_out;

    long long n = (long long)out_size;      // 256*512*256 = 33,554,432 floats
    long long n_vec = n / 4;                // float4 count

    const int block = 256;
    // Cap grid at ~8 blocks/CU * 256 CUs; grid-stride covers the rest.
    long long want = (n_vec + block - 1) / block;
    int grid = (int)(want < 2048 ? want : 2048);
    if (grid < 1) grid = 1;

    fixed_size_agg_copy_kernel<<<grid, block, 0, stream>>>(
        (const float4*)x, (float4*)out, n_vec);

    long long tail_start = n_vec * 4;
    long long tail = n - tail_start;
    if (tail > 0) {
        int tgrid = (int)((tail + block - 1) / block);
        fixed_size_agg_tail_kernel<<<tgrid, block, 0, stream>>>(x, out, tail_start, n);
    }
}

// Round 3
// 45.362 us; speedup vs baseline: 1.0036x; 1.0036x over previous
//
#include <hip/hip_runtime.h>

// FixedSizeAggregation: batch = repeat(arange(B), N_PER) is already sorted with
// equal segments -> stable argsort is the identity -> the op is an exact flat
// copy of x (fp32, 128 MiB) into d_out.
//
// Round 1 counters: FETCH_SIZE = 64 MiB (half of x served by Infinity Cache
// across replays), WRITE_SIZE = 128 MiB. x + out = 256 MiB = exactly L3 size,
// so cached stores evict x. Fix: non-temporal stores -> output lines don't
// allocate in cache, x stays L3-resident, HBM traffic ~= writes only.
//
// Note: __builtin_nontemporal_store requires a native vector type, not HIP's
// HIP_vector_type<float,4> class -> use ext_vector_type(4).

typedef float f32x4 __attribute__((ext_vector_type(4)));

__global__ void fixed_size_agg_copy_nt_kernel(const f32x4* __restrict__ src,
                                              f32x4* __restrict__ dst,
                                              long long n_vec) {
    long long i = (long long)blockIdx.x * blockDim.x + threadIdx.x;
    long long stride = (long long)gridDim.x * blockDim.x;
    for (; i < n_vec; i += stride) {
        f32x4 v = src[i];                        // cached read (L3 serves repeats)
        __builtin_nontemporal_store(v, &dst[i]); // streaming write, no cache alloc
    }
}

__global__ void fixed_size_agg_tail_kernel(const float* __restrict__ src,
                                           float* __restrict__ dst,
                                           long long start, long long n) {
    long long i = start + (long long)blockIdx.x * blockDim.x + threadIdx.x;
    if (i < n) dst[i] = src[i];
}

extern "C" void kernel_launch(void* const* d_in, const int* in_sizes, int n_in,
                              void* d_out, int out_size, void* d_ws, size_t ws_size,
                              hipStream_t stream) {
    const float* x = (const float*)d_in[0];
    float* out = (float*)d_out;

    long long n = (long long)out_size;      // 256*512*256 = 33,554,432 floats
    long long n_vec = n / 4;                // float4 count

    const int block = 256;
    // 2048 blocks x 256 threads across 256 CUs; grid-stride covers the rest.
    long long want = (n_vec + block - 1) / block;
    int grid = (int)(want < 2048 ? want : 2048);
    if (grid < 1) grid = 1;

    fixed_size_agg_copy_nt_kernel<<<grid, block, 0, stream>>>(
        (const f32x4*)x, (f32x4*)out, n_vec);

    long long tail_start = n_vec * 4;
    long long tail = n - tail_start;
    if (tail > 0) {
        int tgrid = (int)((tail + block - 1) / block);
        fixed_size_agg_tail_kernel<<<tgrid, block, 0, stream>>>(x, out, tail_start, n);
    }
}